// Round 2
// baseline (438.641 us; speedup 1.0000x reference)
//
#include <hip/hip_runtime.h>
#include <cstddef>
#include <cstdint>

// MinGRU fused: g/v/d = x@W{g,v,d}^T + b; xs = sigmoid(g)*tanh(v);
// a = 0.001+0.998*sigmoid(d); h_t = a_t*h_{t-1} + xs_t over S. Out f32 [B,S,D].
// B=4, S=4096, D=1024.
//
// Pipeline: cvt_x -> cvt_w -> gemm_fused (GEMM x3 + activations + local chunk
// scan, emits xsA/aA f16 + per-32-row P/H) -> scan2 (chain carries) -> scan3.

typedef _Float16 f16;
typedef f16 f16x4 __attribute__((ext_vector_type(4)));
typedef f16 f16x8 __attribute__((ext_vector_type(8)));
typedef float f32x4 __attribute__((ext_vector_type(4)));

#define S_LEN 4096
#define D_DIM 1024
#define B_DIM 4
#define M_TOT (B_DIM * S_LEN)  // 16384
#define K_TOT D_DIM            // 1024

// GEMM tile
#define BM 128
#define BN 64
// scan chunking: 32 t per chunk, 128 chunks per batch, 512 global
#define CLEN 32
#define CHUNKS_PER_B (S_LEN / CLEN)  // 128
#define NCHUNK (B_DIM * CHUNKS_PER_B)  // 512

// ---------------- f32 -> f16 convert, 8 elems/thread ----------------
__global__ void cvt_f16_kernel(const float* __restrict__ src, f16* __restrict__ dst, int n) {
  int i = (blockIdx.x * blockDim.x + threadIdx.x) * 8;
  if (i >= n) return;
  f32x4 a = *(const f32x4*)(src + i);
  f32x4 b = *(const f32x4*)(src + i + 4);
  f16x8 o;
  o[0] = (f16)a[0]; o[1] = (f16)a[1]; o[2] = (f16)a[2]; o[3] = (f16)a[3];
  o[4] = (f16)b[0]; o[5] = (f16)b[1]; o[6] = (f16)b[2]; o[7] = (f16)b[3];
  *(f16x8*)(dst + i) = o;
}

// 3 weight matrices (1024x1024 each) -> Bh[3][1024][1024] f16
__global__ void cvt_w_kernel(const float* __restrict__ w0, const float* __restrict__ w1,
                             const float* __restrict__ w2, f16* __restrict__ dst) {
  int i = (blockIdx.x * blockDim.x + threadIdx.x) * 8;  // 0..3145720
  int sel = i >> 20;
  int loc = i & 1048575;
  const float* src = (sel == 0) ? w0 : (sel == 1) ? w1 : w2;
  f32x4 a = *(const f32x4*)(src + loc);
  f32x4 b = *(const f32x4*)(src + loc + 4);
  f16x8 o;
  o[0] = (f16)a[0]; o[1] = (f16)a[1]; o[2] = (f16)a[2]; o[3] = (f16)a[3];
  o[4] = (f16)b[0]; o[5] = (f16)b[1]; o[6] = (f16)b[2]; o[7] = (f16)b[3];
  *(f16x8*)(dst + i) = o;
}

__device__ __forceinline__ void gl_lds16(const void* g, void* l) {
  __builtin_amdgcn_global_load_lds((const __attribute__((address_space(1))) void*)g,
                                   (__attribute__((address_space(3))) void*)l, 16, 0, 0);
}

// ---------------- fused GEMM(x3) + activation + local scan ----------------
// Block: 128 rows (consecutive t in one b) x 64 cols of D, all 3 matrices.
// grid = (D/BN=16, M/BM=128), 256 threads.
__global__ __launch_bounds__(256) void gemm_fused_kernel(
    const f16* __restrict__ A, const f16* __restrict__ Bh,
    const float* __restrict__ bg, const float* __restrict__ bv, const float* __restrict__ bd,
    f16* __restrict__ xsA, f16* __restrict__ aA,
    float* __restrict__ P, float* __restrict__ H) {
  __shared__ __attribute__((aligned(16))) char smem[32768];
  f16* As = (f16*)smem;        // 128x32 halves = 8 KB
  f16* Bs = As + 4096;         // 3 x 64x32 halves = 12 KB

  const int tid = threadIdx.x;
  const int lane = tid & 63;
  const int wave = tid >> 6;
  const int m0 = blockIdx.y * BM;
  const int n0 = blockIdx.x * BN;

  // staging source addressing
  const int srow = tid >> 2;       // 0..63
  const int scol = (tid & 3) * 8;  // half index within 32-half row
  const f16* aG0 = A + (size_t)(m0 + srow) * K_TOT + scol;
  const f16* aG1 = A + (size_t)(m0 + srow + 64) * K_TOT + scol;
  const f16* bG0 = Bh + (size_t)(n0 + srow) * K_TOT + scol;                // Wg
  const f16* bG1 = Bh + 1048576 + (size_t)(n0 + srow) * K_TOT + scol;     // Wv
  const f16* bG2 = Bh + 2097152 + (size_t)(n0 + srow) * K_TOT + scol;     // Wd
  f16* aL0 = As + tid * 8;
  f16* aL1 = As + 2048 + tid * 8;
  f16* bL0 = Bs + tid * 8;
  f16* bL1 = Bs + 2048 + tid * 8;
  f16* bL2 = Bs + 4096 + tid * 8;

  const int wm = (wave >> 1) * 64;  // 0 or 64
  const int wn = (wave & 1) * 32;   // 0 or 32
  const int lm = lane & 15;
  const int kq = (lane >> 4) * 8;

  f32x4 acc[3][4][2] = {};

  for (int k0 = 0; k0 < K_TOT; k0 += 32) {
    gl_lds16(aG0 + k0, aL0);
    gl_lds16(aG1 + k0, aL1);
    gl_lds16(bG0 + k0, bL0);
    gl_lds16(bG1 + k0, bL1);
    gl_lds16(bG2 + k0, bL2);
    __syncthreads();
    f16x8 af[4];
#pragma unroll
    for (int i = 0; i < 4; ++i)
      af[i] = *(const f16x8*)&As[(wm + i * 16 + lm) * 32 + kq];
#pragma unroll
    for (int mat = 0; mat < 3; ++mat) {
      f16x8 bf[2];
#pragma unroll
      for (int j = 0; j < 2; ++j)
        bf[j] = *(const f16x8*)&Bs[mat * 2048 + (wn + j * 16 + lm) * 32 + kq];
#pragma unroll
      for (int i = 0; i < 4; ++i)
#pragma unroll
        for (int j = 0; j < 2; ++j)
          acc[mat][i][j] =
              __builtin_amdgcn_mfma_f32_16x16x32_f16(af[i], bf[j], acc[mat][i][j], 0, 0, 0);
    }
    __syncthreads();
  }

  // ---- epilogue: activations into LDS tiles (overlay staging buffers) ----
  f16* xsT = (f16*)smem;       // 128x64 halves = 16 KB
  f16* aT = xsT + 8192;        // 16 KB

  const int cbase = (lane >> 4) * 4;  // row offset within fragment
  float vbg[2], vbv[2], vbd[2];
#pragma unroll
  for (int j = 0; j < 2; ++j) {
    int cn = n0 + wn + j * 16 + lm;
    vbg[j] = bg[cn];
    vbv[j] = bv[cn];
    vbd[j] = bd[cn];
  }
#pragma unroll
  for (int i = 0; i < 4; ++i)
#pragma unroll
    for (int j = 0; j < 2; ++j)
#pragma unroll
      for (int r = 0; r < 4; ++r) {
        int rloc = wm + i * 16 + cbase + r;        // 0..127
        int cloc = wn + j * 16 + lm;               // 0..63
        float g = acc[0][i][j][r] + vbg[j];
        float v = acc[1][i][j][r] + vbv[j];
        float d = acc[2][i][j][r] + vbd[j];
        float sg = 1.f / (1.f + __expf(-g));
        float tv = 1.f - 2.f / (__expf(2.f * v) + 1.f);
        float sd = 1.f / (1.f + __expf(-d));
        xsT[rloc * 64 + cloc] = (f16)(sg * tv);
        aT[rloc * 64 + cloc] = (f16)(0.001f + 0.998f * sd);
      }
  __syncthreads();

  // ---- local scan: 64 threads, one column each, P/H snapshot every 32 rows ----
  if (tid < 64) {
    float h = 0.f, p = 1.f;
#pragma unroll 8
    for (int r = 0; r < 128; ++r) {
      float av = (float)aT[r * 64 + tid];
      float xv = (float)xsT[r * 64 + tid];
      h = av * h + xv;
      p *= av;
      if ((r & 31) == 31) {
        int sub = blockIdx.y * 4 + (r >> 5);  // global chunk 0..511 (ordered by b,t)
        int idx = sub * D_DIM + n0 + tid;
        P[idx] = p;
        H[idx] = h;
        p = 1.f;
        h = 0.f;
      }
    }
  }

  // ---- store xs/a tiles to global (coalesced, 128 B per 8-thread row-chunk) ----
#pragma unroll
  for (int it = 0; it < 4; ++it) {
    int r = (tid >> 3) + it * 32;
    int c = (tid & 7) * 8;
    size_t gidx = (size_t)(m0 + r) * D_DIM + n0 + c;
    *(f16x8*)(xsA + gidx) = *(const f16x8*)&xsT[r * 64 + c];
    *(f16x8*)(aA + gidx) = *(const f16x8*)&aT[r * 64 + c];
  }
}

// ---------------- scan pass 2: chain carries across 128 chunks per batch ----------------
__global__ void scan2_kernel(const float* __restrict__ P, const float* __restrict__ H,
                             float* __restrict__ carry) {
  const int idx = blockIdx.x * 256 + threadIdx.x;  // 0..4095 = b*1024+d
  const int b = idx >> 10;
  const int d = idx & 1023;
  float h = 0.f;
  for (int c = 0; c < CHUNKS_PER_B; ++c) {
    int gs = b * CHUNKS_PER_B + c;
    carry[gs * D_DIM + d] = h;
    h = P[gs * D_DIM + d] * h + H[gs * D_DIM + d];
  }
}

// ---------------- scan pass 3: rescan with carry, write output ----------------
__global__ void scan3_kernel(const f16* __restrict__ xsA, const f16* __restrict__ aA,
                             const float* __restrict__ carry, float* __restrict__ out) {
  const int u = blockIdx.x * 256 + threadIdx.x;
  const int cg = u & 255;
  const int b = (u >> 8) & 3;
  const int ck = u >> 10;  // 0..127
  const int ch = cg * 4;
  const int gs = b * CHUNKS_PER_B + ck;
  f32x4 h = *(const f32x4*)(carry + gs * D_DIM + ch);
  const int t0 = ck * CLEN;
#pragma unroll 4
  for (int t = t0; t < t0 + CLEN; ++t) {
    const size_t m = (size_t)b * S_LEN + t;
    f16x4 xs4 = *(const f16x4*)(xsA + m * D_DIM + ch);
    f16x4 a4 = *(const f16x4*)(aA + m * D_DIM + ch);
#pragma unroll
    for (int j = 0; j < 4; ++j) h[j] = (float)a4[j] * h[j] + (float)xs4[j];
    *(f32x4*)(out + m * D_DIM + ch) = h;
  }
}

extern "C" void kernel_launch(void* const* d_in, const int* in_sizes, int n_in,
                              void* d_out, int out_size, void* d_ws, size_t ws_size,
                              hipStream_t stream) {
  const float* x = (const float*)d_in[0];
  const float* Wg = (const float*)d_in[1];
  const float* bg = (const float*)d_in[2];
  const float* Wv = (const float*)d_in[3];
  const float* bv = (const float*)d_in[4];
  const float* Wd = (const float*)d_in[5];
  const float* bd = (const float*)d_in[6];
  float* out = (float*)d_out;

  // workspace layout (~113 MB)
  char* ws = (char*)d_ws;
  f16* Ah = (f16*)(ws);                     // 33,554,432 B
  f16* Bh = (f16*)(ws + 33554432);          // 6,291,456 B
  f16* xsA = (f16*)(ws + 39845888);         // 33,554,432 B
  f16* aA = (f16*)(ws + 73400320);          // 33,554,432 B
  float* P = (float*)(ws + 106954752);      // 512*1024*4 = 2,097,152 B
  float* H = (float*)(ws + 109051904);      // 2,097,152 B
  float* carry = (float*)(ws + 111149056);  // 2,097,152 B

  cvt_f16_kernel<<<8192, 256, 0, stream>>>(x, Ah, M_TOT * K_TOT);
  cvt_w_kernel<<<1536, 256, 0, stream>>>(Wg, Wv, Wd, Bh);
  gemm_fused_kernel<<<dim3(D_DIM / BN, M_TOT / BM), 256, 0, stream>>>(
      Ah, Bh, bg, bv, bd, xsA, aA, P, H);
  scan2_kernel<<<16, 256, 0, stream>>>(P, H, carry);
  scan3_kernel<<<512, 256, 0, stream>>>(xsA, aA, carry, out);
}

// Round 3
// 338.240 us; speedup vs baseline: 1.2968x; 1.2968x over previous
//
#include <hip/hip_runtime.h>
#include <cstddef>
#include <cstdint>

// MinGRU: g/v/d = x@W{g,v,d}^T + b; xs = sigmoid(g)*tanh(v); a = 0.001+0.998*sigmoid(d)
// h_t = a_t*h_{t-1} + xs_t (causal scan over S). Output h [B,S,D] f32.
// B=4, S=4096, D=1024.
// R3: R1 pipeline (separate GEMM N=3072) + merged cvt + coalesced GEMM epilogue
// via LDS transpose + 16B-load scan kernels (CLEN=16, 8ch/thread).

typedef _Float16 f16;
typedef f16 f16x8 __attribute__((ext_vector_type(8)));
typedef float f32x4 __attribute__((ext_vector_type(4)));

#define S_LEN 4096
#define D_DIM 1024
#define B_DIM 4
#define M_TOT (B_DIM * S_LEN)  // 16384
#define N_TOT (3 * D_DIM)      // 3072
#define K_TOT D_DIM            // 1024

#define CLEN 16
#define CPB (S_LEN / CLEN)   // 256 chunks per batch
#define NCHUNK (B_DIM * CPB) // 1024

// ---------------- merged f32 -> f16 convert: x then Wg|Wv|Wd ----------------
__device__ __forceinline__ void cvt8(const float* s, f16* d) {
  f32x4 a = *(const f32x4*)s;
  f32x4 b = *(const f32x4*)(s + 4);
  f16x8 o;
  o[0] = (f16)a[0]; o[1] = (f16)a[1]; o[2] = (f16)a[2]; o[3] = (f16)a[3];
  o[4] = (f16)b[0]; o[5] = (f16)b[1]; o[6] = (f16)b[2]; o[7] = (f16)b[3];
  *(f16x8*)d = o;
}

__global__ void cvt_all_kernel(const float* __restrict__ x, const float* __restrict__ w0,
                               const float* __restrict__ w1, const float* __restrict__ w2,
                               f16* __restrict__ Ah, f16* __restrict__ Bh) {
  int i = (blockIdx.x * 256 + threadIdx.x) * 8;  // 0 .. 19922936
  if (i < M_TOT * K_TOT) {
    cvt8(x + i, Ah + i);
  } else {
    int w = i - M_TOT * K_TOT;            // 0 .. 3145720
    int sel = w >> 20;
    int loc = w & 1048575;
    const float* s = (sel == 0) ? w0 : (sel == 1) ? w1 : w2;
    cvt8(s + loc, Bh + w);
  }
}

// ---------------- GEMM: C[M,N] = A[M,K] * Bt[N,K]^T, fp16 in, fp16 out ----------------
#define BM 128
#define BN 128
#define BK 32
#define CT_PITCH 136  // halves; 272B row stride: 16B-aligned, <=2-way bank conflicts

__device__ __forceinline__ void gl_lds16(const void* g, void* l) {
  __builtin_amdgcn_global_load_lds((const __attribute__((address_space(1))) void*)g,
                                   (__attribute__((address_space(3))) void*)l, 16, 0, 0);
}

__global__ __launch_bounds__(256) void gemm_f16_kernel(const f16* __restrict__ A,
                                                       const f16* __restrict__ Bt,
                                                       f16* __restrict__ C) {
  // 16 KB staging (As 8K + Bs 8K); epilogue overlays full 128x136 C-tile (34 KB)
  __shared__ __attribute__((aligned(16))) char smem[BM * CT_PITCH * 2];
  f16* As = (f16*)smem;
  f16* Bs = As + 4096;
  const int tid = threadIdx.x;
  const int lane = tid & 63;
  const int wave = tid >> 6;
  const int m0 = blockIdx.y * BM;
  const int n0 = blockIdx.x * BN;

  const int srow = tid >> 2;       // 0..63
  const int scol = (tid & 3) * 8;  // half index within 32-half row
  const f16* aG0 = A + (size_t)(m0 + srow) * K_TOT + scol;
  const f16* aG1 = A + (size_t)(m0 + srow + 64) * K_TOT + scol;
  const f16* bG0 = Bt + (size_t)(n0 + srow) * K_TOT + scol;
  const f16* bG1 = Bt + (size_t)(n0 + srow + 64) * K_TOT + scol;
  f16* aL0 = As + tid * 8;
  f16* aL1 = As + 2048 + tid * 8;
  f16* bL0 = Bs + tid * 8;
  f16* bL1 = Bs + 2048 + tid * 8;

  const int wm = (wave >> 1) * 64;
  const int wn = (wave & 1) * 64;
  const int lm = lane & 15;
  const int kq = (lane >> 4) * 8;

  f32x4 acc[4][4] = {};

  for (int k0 = 0; k0 < K_TOT; k0 += BK) {
    gl_lds16(aG0 + k0, aL0);
    gl_lds16(aG1 + k0, aL1);
    gl_lds16(bG0 + k0, bL0);
    gl_lds16(bG1 + k0, bL1);
    __syncthreads();  // drains vmcnt -> staging visible
    f16x8 af[4], bf[4];
#pragma unroll
    for (int i = 0; i < 4; ++i)
      af[i] = *(const f16x8*)&As[(wm + i * 16 + lm) * BK + kq];
#pragma unroll
    for (int j = 0; j < 4; ++j)
      bf[j] = *(const f16x8*)&Bs[(wn + j * 16 + lm) * BK + kq];
#pragma unroll
    for (int i = 0; i < 4; ++i)
#pragma unroll
      for (int j = 0; j < 4; ++j)
        acc[i][j] = __builtin_amdgcn_mfma_f32_16x16x32_f16(af[i], bf[j], acc[i][j], 0, 0, 0);
    __syncthreads();  // protect LDS before next stage / epilogue overlay
  }

  // epilogue: acc -> LDS tile (C/D layout: col=lane&15, row=(lane>>4)*4+reg),
  // then coalesced f16x8 global stores.
  f16* Ct = (f16*)smem;
  const int r0 = wm + (lane >> 4) * 4;
  const int c0 = wn + (lane & 15);
#pragma unroll
  for (int i = 0; i < 4; ++i)
#pragma unroll
    for (int j = 0; j < 4; ++j)
#pragma unroll
      for (int r = 0; r < 4; ++r)
        Ct[(r0 + i * 16 + r) * CT_PITCH + c0 + j * 16] = (f16)acc[i][j][r];
  __syncthreads();
#pragma unroll
  for (int p = 0; p < 8; ++p) {
    int row = p * 16 + (tid >> 4);
    int col = (tid & 15) * 8;
    *(f16x8*)(C + (size_t)(m0 + row) * N_TOT + n0 + col) =
        *(const f16x8*)&Ct[row * CT_PITCH + col];
  }
}

// ---------------- scan pass 1: activations + per-chunk local scan ----------------
// thread: 8 channels x 16 timesteps; u = [ck:8][b:2][cg:7], 131072 threads.
__global__ void scan1_kernel(const f16* __restrict__ G, const float* __restrict__ bg,
                             const float* __restrict__ bv, const float* __restrict__ bd,
                             f16* __restrict__ xsA, f16* __restrict__ aA,
                             float* __restrict__ P, float* __restrict__ H) {
  const int u = blockIdx.x * 256 + threadIdx.x;
  const int cg = u & 127;
  const int b = (u >> 7) & 3;
  const int ck = u >> 9;  // 0..255
  const int ch = cg * 8;
  float vbg[8], vbv[8], vbd[8];
  *(f32x4*)vbg = *(const f32x4*)(bg + ch); *(f32x4*)(vbg + 4) = *(const f32x4*)(bg + ch + 4);
  *(f32x4*)vbv = *(const f32x4*)(bv + ch); *(f32x4*)(vbv + 4) = *(const f32x4*)(bv + ch + 4);
  *(f32x4*)vbd = *(const f32x4*)(bd + ch); *(f32x4*)(vbd + 4) = *(const f32x4*)(bd + ch + 4);
  float h[8] = {}, p[8] = {1.f, 1.f, 1.f, 1.f, 1.f, 1.f, 1.f, 1.f};
  const int t0 = ck * CLEN;
#pragma unroll 2
  for (int t = t0; t < t0 + CLEN; ++t) {
    const size_t m = (size_t)b * S_LEN + t;
    const f16* gp = G + m * N_TOT + ch;
    f16x8 g8 = *(const f16x8*)gp;
    f16x8 v8 = *(const f16x8*)(gp + D_DIM);
    f16x8 d8 = *(const f16x8*)(gp + 2 * D_DIM);
    f16x8 xs8, a8;
#pragma unroll
    for (int j = 0; j < 8; ++j) {
      float gg = (float)g8[j] + vbg[j];
      float vv = (float)v8[j] + vbv[j];
      float dd = (float)d8[j] + vbd[j];
      float sg = 1.f / (1.f + __expf(-gg));
      float tv = 1.f - 2.f / (__expf(2.f * vv) + 1.f);
      float sd = 1.f / (1.f + __expf(-dd));
      f16 xh = (f16)(sg * tv);
      f16 ah = (f16)(0.001f + 0.998f * sd);
      // use ROUNDED values so pass-3 recomposition is exactly consistent
      float xsr = (float)xh, avr = (float)ah;
      h[j] = avr * h[j] + xsr;
      p[j] *= avr;
      xs8[j] = xh;
      a8[j] = ah;
    }
    *(f16x8*)(xsA + m * D_DIM + ch) = xs8;
    *(f16x8*)(aA + m * D_DIM + ch) = a8;
  }
  const int base = (b * CPB + ck) * D_DIM + ch;
  *(f32x4*)(P + base) = *(f32x4*)p;
  *(f32x4*)(P + base + 4) = *(f32x4*)(p + 4);
  *(f32x4*)(H + base) = *(f32x4*)h;
  *(f32x4*)(H + base + 4) = *(f32x4*)(h + 4);
}

// ---------------- scan pass 2: chain carries across 256 chunks per batch ----------------
__global__ void scan2_kernel(const float* __restrict__ P, const float* __restrict__ H,
                             float* __restrict__ carry) {
  const int idx = blockIdx.x * 256 + threadIdx.x;  // 0..4095 = b*1024+d
  const int b = idx >> 10;
  const int d = idx & 1023;
  float h = 0.f;
  for (int c = 0; c < CPB; ++c) {
    int gs = b * CPB + c;
    carry[gs * D_DIM + d] = h;
    h = P[gs * D_DIM + d] * h + H[gs * D_DIM + d];
  }
}

// ---------------- scan pass 3: rescan with carry, write output ----------------
__global__ void scan3_kernel(const f16* __restrict__ xsA, const f16* __restrict__ aA,
                             const float* __restrict__ carry, float* __restrict__ out) {
  const int u = blockIdx.x * 256 + threadIdx.x;
  const int cg = u & 127;
  const int b = (u >> 7) & 3;
  const int ck = u >> 9;
  const int ch = cg * 8;
  const int base = (b * CPB + ck) * D_DIM + ch;
  float h[8];
  *(f32x4*)h = *(const f32x4*)(carry + base);
  *(f32x4*)(h + 4) = *(const f32x4*)(carry + base + 4);
  const int t0 = ck * CLEN;
#pragma unroll 2
  for (int t = t0; t < t0 + CLEN; ++t) {
    const size_t m = (size_t)b * S_LEN + t;
    f16x8 xs8 = *(const f16x8*)(xsA + m * D_DIM + ch);
    f16x8 a8 = *(const f16x8*)(aA + m * D_DIM + ch);
#pragma unroll
    for (int j = 0; j < 8; ++j) h[j] = (float)a8[j] * h[j] + (float)xs8[j];
    float* op = out + m * D_DIM + ch;
    *(f32x4*)op = *(f32x4*)h;
    *(f32x4*)(op + 4) = *(f32x4*)(h + 4);
  }
}

extern "C" void kernel_launch(void* const* d_in, const int* in_sizes, int n_in,
                              void* d_out, int out_size, void* d_ws, size_t ws_size,
                              hipStream_t stream) {
  const float* x = (const float*)d_in[0];
  const float* Wg = (const float*)d_in[1];
  const float* bg = (const float*)d_in[2];
  const float* Wv = (const float*)d_in[3];
  const float* bv = (const float*)d_in[4];
  const float* Wd = (const float*)d_in[5];
  const float* bd = (const float*)d_in[6];
  float* out = (float*)d_out;

  // workspace layout (207,618,048 B total).
  // Ah region (0..33.5MB) is dead after the GEMM; P/H/carry overlay it
  // (scan1 runs strictly after gemm in stream order).
  char* ws = (char*)d_ws;
  f16* Ah = (f16*)(ws);                     // 33,554,432 B (cvt -> gemm only)
  float* P = (float*)(ws);                  // 4,194,304 B  (overlay, scan1+)
  float* H = (float*)(ws + 4194304);        // 4,194,304 B
  float* carry = (float*)(ws + 8388608);    // 4,194,304 B
  f16* Bh = (f16*)(ws + 33554432);          // 6,291,456 B
  f16* Gh = (f16*)(ws + 39845888);          // 100,663,296 B
  f16* xsA = (f16*)(ws + 140509184);        // 33,554,432 B
  f16* aA = (f16*)(ws + 174063616);         // 33,554,432 B

  // (16384*1024 + 3*1024*1024) / 8 / 256 = 9728 blocks, exact
  cvt_all_kernel<<<9728, 256, 0, stream>>>(x, Wg, Wv, Wd, Ah, Bh);
  gemm_f16_kernel<<<dim3(N_TOT / BN, M_TOT / BM), 256, 0, stream>>>(Ah, Bh, Gh);
  scan1_kernel<<<512, 256, 0, stream>>>(Gh, bg, bv, bd, xsA, aA, P, H);
  scan2_kernel<<<16, 256, 0, stream>>>(P, H, carry);
  scan3_kernel<<<512, 256, 0, stream>>>(xsA, aA, carry, out);
}